// Round 13
// baseline (77.332 us; speedup 1.0000x reference)
//
#include <hip/hip_runtime.h>
#include <stdint.h>

// FFM: B=4096, F=20 fields x S=500 feats, K=16.
// E2[b, i*336 + g*16 + k] = sum_s x[b,i*500+s]*v[g,i*500+s,k]  (g<20)
// E2[b, i*336 + 320]      = sum_s x[b,i*500+s]*w[i*500+s]      (linear partial)
// out[b] = sum_i E2[b,i,320] + sum_{i<j,k} E2[b,i*336+j*16+k]*E2[b,j*336+i*16+k]

#define NF 20
#define FS 500
#define TFEAT 10000
#define KD 16
#define NCOL 336        // 21 frags: 320 interaction cols + 16-col w block
#define NFRG 21
#define KP 512
#define NB 4096
#define ROWE (NF * NCOL)  // 6720

typedef __bf16 bf16x8 __attribute__((ext_vector_type(8)));
typedef __bf16 bf16x2 __attribute__((ext_vector_type(2)));
typedef float  f32x4  __attribute__((ext_vector_type(4)));
typedef unsigned int u32x4 __attribute__((ext_vector_type(4)));

typedef __attribute__((address_space(1))) const void* as1cv;
typedef __attribute__((address_space(3))) void* as3v;

__device__ inline void gload_lds16(const void* g, void* l) {
  __builtin_amdgcn_global_load_lds((as1cv)g, (as3v)l, 16, 0, 0);
}

// ---------------- prep: VtS in STAGED order (unchanged from R9-R12).
// VtS[((i*16+t32)*21+q)*512 + l*8 + e] = B-panel value for row n=16q+(l>>2),
// kk = t32*32 + ((l&3)^((l>>3)&3))*8 + e.  n<320 -> v; n==320 -> w; else 0.
__global__ __launch_bounds__(256) void prep_vt(const float* __restrict__ v,
                                               const float* __restrict__ w,
                                               __bf16* __restrict__ VtS) {
  const int i = blockIdx.x / NFRG;
  const int q = blockIdx.x % NFRG;
  const int tdx = threadIdx.x;
  __shared__ float lv[FS * 17];
  if (q < NF) {  // panel for g=q: lv[s*17+k] = v[g, i*500+s, k]
    const int k = tdx & 15, sb = tdx >> 4;
    const float* vb = v + ((size_t)q * TFEAT + (size_t)i * FS) * KD;
    for (int it = 0; it < 32; ++it) {
      int s = it * 16 + sb;
      if (s < FS) lv[s * 17 + k] = vb[(size_t)s * KD + k];
    }
    __syncthreads();
  }
  const float* wf = w + (size_t)i * FS;
  __bf16* base = VtS + ((size_t)i * 16 * NFRG + q) * 512;
  for (int it = 0; it < 4; ++it) {
    int p = it * 256 + tdx;            // (t32,l) pair: 16*64 = 1024
    int t = p >> 6, l = p & 63;
    int r = l >> 2;                    // row within group (= k for q<20)
    int kk = t * 32 + (((l & 3) ^ ((l >> 3) & 3)) << 3);
    bf16x8 h;
#pragma unroll
    for (int e = 0; e < 8; ++e) {
      int s = kk + e;
      float val = 0.f;
      if (s < FS) {
        if (q < NF) val = lv[s * 17 + r];
        else if (r == 0) val = wf[s];
      }
      h[e] = (__bf16)val;
    }
    *(bf16x8*)(base + (size_t)t * (NFRG * 512) + l * 8) = h;
  }
}

// ---------------- K1: per-field GEMM. BM=64, BN=336, BK=64, 8 K-steps, 4 waves.
// HALF-TILE PIPELINE: phase (t,h) computes k-half h of tile t while the glds
// for the NEXT half (issued at phase start, into the buffer read 2 phases ago)
// are in flight. Drains are one full compute-phase old. 2 barriers/K-step.
// A reg-staged: aload(t+1) at Phase(t,0); ah=0 threads astore at Phase(t,1),
// ah=1 at Phase(t+1,0). setprio(1) around MFMA clusters (T5).
// LDS 51.2 KB -> 3 blocks/CU. XCD-bijective swizzle.
__global__ __launch_bounds__(256, 3) void k1_gemm(
    const float* __restrict__ x, const __bf16* __restrict__ VtS,
    __bf16* __restrict__ E2, int chunk_base, int tiles) {
  __shared__ __bf16 As[2][64][32];        // k-halves, 8192 B
  __shared__ __bf16 Bs[2][NCOL * 32];     // k-halves, 43008 B

  int bid = blockIdx.x;
  const int nwg = gridDim.x;
  if ((nwg & 7) == 0) {                   // bijective XCD swizzle
    int cpx = nwg >> 3;
    bid = (bid & 7) * cpx + (bid >> 3);
  }
  const int i  = bid / tiles;
  const int tb = bid % tiles;
  const int tid = threadIdx.x;
  const int lane = tid & 63, wid = tid >> 6;
  const int b0 = chunk_base + tb * 64;

  // A stage (per thread): row = tid>>2, 16 f32 cols at (tid&3)*16 within 64-step
  const int arow = tid >> 2;
  const int ac16 = (tid & 3) * 16;
  const int ah  = (tid & 3) >> 1;                  // k-half this thread writes
  const int gh0 = (2 * (tid & 3)) & 3;             // granule-in-half (0 or 2)
  const int rsw = (arow >> 1) & 3;                 // row swizzle
  const float* xrow = x + (size_t)(b0 + arow) * TFEAT + i * FS;
  const __bf16* VtSi = VtS + (size_t)i * 16 * NFRG * 512 + lane * 8;

  auto issueBhalf = [&](int t32) {   // stage 32-substep t32 into Bs[t32&1]
    __bf16* dst = &Bs[t32 & 1][0];
#pragma unroll
    for (int jj = 0; jj < 6; ++jj) {
      int q = wid + 4 * jj;
      if (q < NFRG)
        gload_lds16(VtSi + ((size_t)t32 * NFRG + q) * 512, (void*)(dst + q * 512));
    }
  };

  f32x4 ar_[4];
  auto aload = [&](int t) {
#pragma unroll
    for (int j = 0; j < 4; ++j) {
      int c = t * 64 + ac16 + j * 4;
      if (c > 496) c = 496;              // clamp: junk cols pair with zero B rows
      ar_[j] = *(const f32x4*)(xrow + c);
    }
  };
  auto astoreH = [&](int half) {         // only threads owning this k-half write
    if (ah == half) {
      bf16x8 h0, h1;
#pragma unroll
      for (int e = 0; e < 4; ++e) {
        h0[e] = (__bf16)ar_[0][e]; h0[4 + e] = (__bf16)ar_[1][e];
        h1[e] = (__bf16)ar_[2][e]; h1[4 + e] = (__bf16)ar_[3][e];
      }
      *(bf16x8*)(&As[ah][arow][((gh0)     ^ rsw) * 8]) = h0;
      *(bf16x8*)(&As[ah][arow][((gh0 + 1) ^ rsw) * 8]) = h1;
    }
  };

  const int nfr = wid ? 5 : 6;
  const int Fbase = wid ? (1 + wid * 5) : 0;
  const int ar = lane & 15, akc = lane >> 4;

  f32x4 acc[4][6];
#pragma unroll
  for (int m = 0; m < 4; ++m)
#pragma unroll
    for (int nf = 0; nf < 6; ++nf) acc[m][nf] = (f32x4){0.f, 0.f, 0.f, 0.f};

  auto compute = [&](int h) {
    __builtin_amdgcn_s_setprio(1);
    bf16x8 af[4];
#pragma unroll
    for (int m = 0; m < 4; ++m) {
      int row = m * 16 + ar;
      int pch = akc ^ ((row >> 1) & 3);
      af[m] = *(const bf16x8*)(&As[h][row][pch * 8]);
    }
#pragma unroll
    for (int nf = 0; nf < 6; ++nf)
      if (nf < nfr) {
        int n_ = (Fbase + nf) * 16 + ar;
        int pc = akc ^ ((n_ >> 1) & 3);
        bf16x8 bfr = *(const bf16x8*)&Bs[h][n_ * 32 + pc * 8];
#pragma unroll
        for (int m = 0; m < 4; ++m)
          acc[m][nf] = __builtin_amdgcn_mfma_f32_16x16x32_bf16(af[m], bfr,
                                                               acc[m][nf], 0, 0, 0);
      }
    __builtin_amdgcn_s_setprio(0);
  };

  // prologue: aload(0); As[0](0) by ah=0; Bs[0]<-(0,0). One exposed drain.
  aload(0);
  issueBhalf(0);
  astoreH(0);                            // ah=0: waits own aloads, leaves glds
  asm volatile("s_waitcnt vmcnt(0) lgkmcnt(0)" ::: "memory");
  __builtin_amdgcn_s_barrier();

  for (int t = 0; t < 8; ++t) {
    // ---- Phase(t,0): compute half0; stage Bs[1]<-(t,1), As[1]<-(t), aload(t+1)
    issueBhalf(2 * t + 1);
    __builtin_amdgcn_sched_barrier(0);
    astoreH(1);                          // ah=1: regs aload(t), 2 phases old
    if (t < 7) aload(t + 1);             // newest 4 vm-ops
    __builtin_amdgcn_sched_barrier(0);
    compute(0);
    if (t < 7)
      asm volatile("s_waitcnt vmcnt(4) lgkmcnt(0)" ::: "memory");  // leave aloads
    else
      asm volatile("s_waitcnt vmcnt(0) lgkmcnt(0)" ::: "memory");
    __builtin_amdgcn_s_barrier();

    // ---- Phase(t,1): compute half1; stage Bs[0]<-(t+1,0), As[0]<-(t+1)
    if (t < 7) {
      issueBhalf(2 * t + 2);
      __builtin_amdgcn_sched_barrier(0);
      astoreH(0);                        // ah=0: regs aload(t+1), 1 phase old
    }
    __builtin_amdgcn_sched_barrier(0);
    compute(1);
    if (t < 7) {
      asm volatile("s_waitcnt vmcnt(0) lgkmcnt(0)" ::: "memory");
      __builtin_amdgcn_s_barrier();
    }
  }

  // epilogue: C/D layout col=lane&15, row=(lane>>4)*4+r
  const int lr4 = akc * 4, lcol = lane & 15;
#pragma unroll
  for (int m = 0; m < 4; ++m)
#pragma unroll
    for (int nf = 0; nf < 6; ++nf)
      if (nf < nfr) {
        int n = (Fbase + nf) * 16 + lcol;
#pragma unroll
        for (int r = 0; r < 4; ++r) {
          int bl = tb * 64 + m * 16 + lr4 + r;
          E2[(size_t)bl * ROWE + i * NCOL + n] = (__bf16)acc[m][nf][r];
        }
      }
}

// ---------------- K2: pair + linear reduction, 1 wave per batch row
__global__ __launch_bounds__(256) void k2_pair(
    const __bf16* __restrict__ E2, float* __restrict__ out, int chunk_base) {
  __shared__ __align__(16) unsigned shw[4][3360];  // 13440 B per wave
  const int tid = threadIdx.x, lane = tid & 63, wid = tid >> 6;
  const int bl = blockIdx.x * 4 + wid;
  const unsigned* src = (const unsigned*)(E2 + (size_t)bl * ROWE);
  for (int it = 0; it < 14; ++it) {
    int idx = it * 64 + lane;             // 16B units; 840 total
    if (idx < 840) {
      u32x4 val = *(const u32x4*)(src + (size_t)idx * 4);
      *(u32x4*)&shw[wid][idx * 4] = val;
    }
  }
  __syncthreads();
  const __bf16* sh = (const __bf16*)shw[wid];
  const int k = lane & 15, g = lane >> 4;
  float sum = 0.f;
  for (int i = g; i < NF; i += 4)
    for (int j = i + 1; j < NF; ++j)
      sum += (float)sh[i * NCOL + j * 16 + k] * (float)sh[j * NCOL + i * 16 + k];
  if (lane < NF) sum += (float)sh[lane * NCOL + 320];   // linear term
#pragma unroll
  for (int off = 32; off; off >>= 1) sum += __shfl_xor(sum, off);
  if (lane == 0) out[chunk_base + bl] = sum;
}

extern "C" void kernel_launch(void* const* d_in, const int* in_sizes, int n_in,
                              void* d_out, int out_size, void* d_ws, size_t ws_size,
                              hipStream_t stream) {
  const float* x = (const float*)d_in[0];
  const float* w = (const float*)d_in[1];
  const float* v = (const float*)d_in[2];
  float* out = (float*)d_out;
  char* ws = (char*)d_ws;

  const size_t vt_bytes = (size_t)NF * 16 * NFRG * 512 * 2;   // 6,881,280
  __bf16* VtS = (__bf16*)ws;
  __bf16* E2 = (__bf16*)(ws + vt_bytes);

  size_t eavail = (ws_size > vt_bytes) ? ws_size - vt_bytes : 0;
  int Bc = NB;
  while (Bc > 64 && (size_t)Bc * ROWE * 2 > eavail) Bc >>= 1;

  prep_vt<<<NF * NFRG, 256, 0, stream>>>(v, w, VtS);
  for (int cb = 0; cb < NB; cb += Bc) {
    int tiles = Bc / 64;
    k1_gemm<<<NF * tiles, 256, 0, stream>>>(x, VtS, E2, cb, tiles);
    k2_pair<<<Bc / 4, 256, 0, stream>>>(E2, out, cb);
  }
}

// Round 14
// 75.756 us; speedup vs baseline: 1.0208x; 1.0208x over previous
//
#include <hip/hip_runtime.h>
#include <stdint.h>

// FFM: B=4096, F=20 fields x S=500 feats, K=16.
// E2[b, i*336 + g*16 + k] = sum_s x[b,i*500+s]*v[g,i*500+s,k]  (g<20)
// E2[b, i*336 + 320]      = sum_s x[b,i*500+s]*w[i*500+s]      (linear partial)
// out[b] = sum_i E2[b,i,320] + sum_{i<j,k} E2[b,i*336+j*16+k]*E2[b,j*336+i*16+k]

#define NF 20
#define FS 500
#define TFEAT 10000
#define KD 16
#define NCOL 336        // 21 frags: 320 interaction cols + 16-col w block
#define NFRG 21
#define KP 512
#define NB 4096
#define ROWE (NF * NCOL)  // 6720

typedef __bf16 bf16x8 __attribute__((ext_vector_type(8)));
typedef __bf16 bf16x2 __attribute__((ext_vector_type(2)));
typedef float  f32x4  __attribute__((ext_vector_type(4)));
typedef unsigned int u32x4 __attribute__((ext_vector_type(4)));

typedef __attribute__((address_space(1))) const void* as1cv;
typedef __attribute__((address_space(3))) void* as3v;

__device__ inline void gload_lds16(const void* g, void* l) {
  __builtin_amdgcn_global_load_lds((as1cv)g, (as3v)l, 16, 0, 0);
}

// ---------------- prep: VtS in STAGED order (unchanged from R9-R12).
// VtS[((i*16+t32)*21+q)*512 + l*8 + e] = B-panel value for row n=16q+(l>>2),
// kk = t32*32 + ((l&3)^((l>>3)&3))*8 + e.  n<320 -> v; n==320 -> w; else 0.
__global__ __launch_bounds__(256) void prep_vt(const float* __restrict__ v,
                                               const float* __restrict__ w,
                                               __bf16* __restrict__ VtS) {
  const int i = blockIdx.x / NFRG;
  const int q = blockIdx.x % NFRG;
  const int tdx = threadIdx.x;
  __shared__ float lv[FS * 17];
  if (q < NF) {  // panel for g=q: lv[s*17+k] = v[g, i*500+s, k]
    const int k = tdx & 15, sb = tdx >> 4;
    const float* vb = v + ((size_t)q * TFEAT + (size_t)i * FS) * KD;
    for (int it = 0; it < 32; ++it) {
      int s = it * 16 + sb;
      if (s < FS) lv[s * 17 + k] = vb[(size_t)s * KD + k];
    }
    __syncthreads();
  }
  const float* wf = w + (size_t)i * FS;
  __bf16* base = VtS + ((size_t)i * 16 * NFRG + q) * 512;
  for (int it = 0; it < 4; ++it) {
    int p = it * 256 + tdx;            // (t32,l) pair: 16*64 = 1024
    int t = p >> 6, l = p & 63;
    int r = l >> 2;                    // row within group (= k for q<20)
    int kk = t * 32 + (((l & 3) ^ ((l >> 3) & 3)) << 3);
    bf16x8 h;
#pragma unroll
    for (int e = 0; e < 8; ++e) {
      int s = kk + e;
      float val = 0.f;
      if (s < FS) {
        if (q < NF) val = lv[s * 17 + r];
        else if (r == 0) val = wf[s];
      }
      h[e] = (__bf16)val;
    }
    *(bf16x8*)(base + (size_t)t * (NFRG * 512) + l * 8) = h;
  }
}

// ---------------- K1: per-field GEMM. BM=64, BN=336, BK=64, 8 K-steps, 4 waves.
// R12 structure + distance-2 A reg ping-pong + counted drain:
// stage region = barrier; issueB(t+1) [12 glds]; astore(tile t+1, regs 1 iter
// old -> HBM covered]; aload(t+2) [4 newest]; vmcnt(4) [drains glds aged by
// astore, leaves aloads in flight]; barrier. vmcnt never 0 until tail.
// LDS 51.2 KB -> 3 blocks/CU. XCD-bijective swizzle. 0 A-conflicts layout.
__global__ __launch_bounds__(256, 3) void k1_gemm(
    const float* __restrict__ x, const __bf16* __restrict__ VtS,
    __bf16* __restrict__ E2, int chunk_base, int tiles) {
  __shared__ __bf16 As[2][64][32];        // k-halves, 8192 B
  __shared__ __bf16 Bs[2][NCOL * 32];     // k-halves, 43008 B

  int bid = blockIdx.x;
  const int nwg = gridDim.x;
  if ((nwg & 7) == 0) {                   // bijective XCD swizzle
    int cpx = nwg >> 3;
    bid = (bid & 7) * cpx + (bid >> 3);
  }
  const int i  = bid / tiles;
  const int tb = bid % tiles;
  const int tid = threadIdx.x;
  const int lane = tid & 63, wid = tid >> 6;
  const int b0 = chunk_base + tb * 64;

  // A stage (per thread): row = tid>>2, 16 f32 cols at (tid&3)*16 within 64-step
  const int arow = tid >> 2;
  const int ac16 = (tid & 3) * 16;
  const int ah  = (tid & 3) >> 1;                  // k-half this thread writes
  const int gh0 = (2 * (tid & 3)) & 3;             // granule-in-half (0 or 2)
  const int rsw = (arow >> 1) & 3;                 // row swizzle
  const float* xrow = x + (size_t)(b0 + arow) * TFEAT + i * FS;
  const __bf16* VtSi = VtS + (size_t)i * 16 * NFRG * 512 + lane * 8;

  auto issueB = [&](int t) {   // stage substeps 2t,2t+1 into halves 0,1
#pragma unroll
    for (int jj = 0; jj < 6; ++jj) {
      int q = wid + 4 * jj;
      if (q < NFRG) {
        gload_lds16(VtSi + ((size_t)(2 * t) * NFRG + q) * 512,
                    (void*)&Bs[0][q * 512]);
        gload_lds16(VtSi + ((size_t)(2 * t + 1) * NFRG + q) * 512,
                    (void*)&Bs[1][q * 512]);
      }
    }
  };

  f32x4 arA[4], arB[4];   // two named prefetch sets (static indexing only)
  auto aload = [&](int t, f32x4* r) {
#pragma unroll
    for (int j = 0; j < 4; ++j) {
      int c = t * 64 + ac16 + j * 4;
      if (c > 496) c = 496;              // clamp: junk cols pair with zero B rows
      r[j] = *(const f32x4*)(xrow + c);
    }
  };
  auto astore = [&](const f32x4* r) {
    bf16x8 h0, h1;
#pragma unroll
    for (int e = 0; e < 4; ++e) {
      h0[e] = (__bf16)r[0][e]; h0[4 + e] = (__bf16)r[1][e];
      h1[e] = (__bf16)r[2][e]; h1[4 + e] = (__bf16)r[3][e];
    }
    *(bf16x8*)(&As[ah][arow][((gh0)     ^ rsw) * 8]) = h0;
    *(bf16x8*)(&As[ah][arow][((gh0 + 1) ^ rsw) * 8]) = h1;
  };

  const int nfr = wid ? 5 : 6;
  const int Fbase = wid ? (1 + wid * 5) : 0;
  const int ar = lane & 15, akc = lane >> 4;

  f32x4 acc[4][6];
#pragma unroll
  for (int m = 0; m < 4; ++m)
#pragma unroll
    for (int nf = 0; nf < 6; ++nf) acc[m][nf] = (f32x4){0.f, 0.f, 0.f, 0.f};

  // prologue: tile0 staged from arA; aload(1)->arB left in flight
  aload(0, arA);
  issueB(0);
  astore(arA);                           // implicit wait on arA only
  __builtin_amdgcn_sched_barrier(0);
  aload(1, arB);                         // newest
  __builtin_amdgcn_sched_barrier(0);
  asm volatile("s_waitcnt vmcnt(4) lgkmcnt(0)" ::: "memory");
  __builtin_amdgcn_s_barrier();

#pragma unroll
  for (int t = 0; t < 8; ++t) {
#pragma unroll
    for (int ks = 0; ks < 2; ++ks) {
      bf16x8 af[4];
#pragma unroll
      for (int m = 0; m < 4; ++m) {
        int row = m * 16 + ar;
        int pch = akc ^ ((row >> 1) & 3);
        af[m] = *(const bf16x8*)(&As[ks][row][pch * 8]);
      }
#pragma unroll
      for (int nf = 0; nf < 6; ++nf)
        if (nf < nfr) {
          int n_ = (Fbase + nf) * 16 + ar;
          int pc = akc ^ ((n_ >> 1) & 3);
          bf16x8 bfr = *(const bf16x8*)&Bs[ks][n_ * 32 + pc * 8];
#pragma unroll
          for (int m = 0; m < 4; ++m)
            acc[m][nf] = __builtin_amdgcn_mfma_f32_16x16x32_bf16(af[m], bfr,
                                                                 acc[m][nf], 0, 0, 0);
        }
    }
    if (t < 7) {
      __builtin_amdgcn_s_barrier();      // all waves done reading LDS tile t
      issueB(t + 1);                     // 12 glds, oldest of this stage region
      if (t & 1) astore(arA); else astore(arB);   // tile t+1 regs, 1 iter old
      __builtin_amdgcn_sched_barrier(0);
      if (t < 6) {                       // newest: 4 aloads for tile t+2
        if (t & 1) aload(t + 2, arB); else aload(t + 2, arA);
      }
      __builtin_amdgcn_sched_barrier(0);
      if (t < 6)
        asm volatile("s_waitcnt vmcnt(4) lgkmcnt(0)" ::: "memory");  // counted
      else
        asm volatile("s_waitcnt vmcnt(0) lgkmcnt(0)" ::: "memory");  // tail
      __builtin_amdgcn_s_barrier();      // tile t+1 ready
    }
  }

  // epilogue: C/D layout col=lane&15, row=(lane>>4)*4+r
  const int lr4 = akc * 4, lcol = lane & 15;
#pragma unroll
  for (int m = 0; m < 4; ++m)
#pragma unroll
    for (int nf = 0; nf < 6; ++nf)
      if (nf < nfr) {
        int n = (Fbase + nf) * 16 + lcol;
#pragma unroll
        for (int r = 0; r < 4; ++r) {
          int bl = tb * 64 + m * 16 + lr4 + r;
          E2[(size_t)bl * ROWE + i * NCOL + n] = (__bf16)acc[m][nf][r];
        }
      }
}

// ---------------- K2: pair + linear reduction, 1 wave per batch row
__global__ __launch_bounds__(256) void k2_pair(
    const __bf16* __restrict__ E2, float* __restrict__ out, int chunk_base) {
  __shared__ __align__(16) unsigned shw[4][3360];  // 13440 B per wave
  const int tid = threadIdx.x, lane = tid & 63, wid = tid >> 6;
  const int bl = blockIdx.x * 4 + wid;
  const unsigned* src = (const unsigned*)(E2 + (size_t)bl * ROWE);
  for (int it = 0; it < 14; ++it) {
    int idx = it * 64 + lane;             // 16B units; 840 total
    if (idx < 840) {
      u32x4 val = *(const u32x4*)(src + (size_t)idx * 4);
      *(u32x4*)&shw[wid][idx * 4] = val;
    }
  }
  __syncthreads();
  const __bf16* sh = (const __bf16*)shw[wid];
  const int k = lane & 15, g = lane >> 4;
  float sum = 0.f;
  for (int i = g; i < NF; i += 4)
    for (int j = i + 1; j < NF; ++j)
      sum += (float)sh[i * NCOL + j * 16 + k] * (float)sh[j * NCOL + i * 16 + k];
  if (lane < NF) sum += (float)sh[lane * NCOL + 320];   // linear term
#pragma unroll
  for (int off = 32; off; off >>= 1) sum += __shfl_xor(sum, off);
  if (lane == 0) out[chunk_base + bl] = sum;
}

extern "C" void kernel_launch(void* const* d_in, const int* in_sizes, int n_in,
                              void* d_out, int out_size, void* d_ws, size_t ws_size,
                              hipStream_t stream) {
  const float* x = (const float*)d_in[0];
  const float* w = (const float*)d_in[1];
  const float* v = (const float*)d_in[2];
  float* out = (float*)d_out;
  char* ws = (char*)d_ws;

  const size_t vt_bytes = (size_t)NF * 16 * NFRG * 512 * 2;   // 6,881,280
  __bf16* VtS = (__bf16*)ws;
  __bf16* E2 = (__bf16*)(ws + vt_bytes);

  size_t eavail = (ws_size > vt_bytes) ? ws_size - vt_bytes : 0;
  int Bc = NB;
  while (Bc > 64 && (size_t)Bc * ROWE * 2 > eavail) Bc >>= 1;

  prep_vt<<<NF * NFRG, 256, 0, stream>>>(v, w, VtS);
  for (int cb = 0; cb < NB; cb += Bc) {
    int tiles = Bc / 64;
    k1_gemm<<<NF * tiles, 256, 0, stream>>>(x, VtS, E2, cb, tiles);
    k2_pair<<<Bc / 4, 256, 0, stream>>>(E2, out, cb);
  }
}

// Round 15
// 72.893 us; speedup vs baseline: 1.0609x; 1.0393x over previous
//
#include <hip/hip_runtime.h>
#include <stdint.h>

// FFM: B=4096, F=20 fields x S=500 feats, K=16.
// E2[b, i*336 + g*16 + k] = sum_s x[b,i*500+s]*v[g,i*500+s,k]  (g<20)
// E2[b, i*336 + 320]      = sum_s x[b,i*500+s]*w[i*500+s]      (linear partial)
// out[b] = sum_i E2[b,i,320] + sum_{i<j,k} E2[b,i*336+j*16+k]*E2[b,j*336+i*16+k]

#define NF 20
#define FS 500
#define TFEAT 10000
#define KD 16
#define NCOL 336        // 21 frags: 320 interaction cols + 16-col w block
#define NFRG 21
#define NB 4096
#define ROWE (NF * NCOL)  // 6720

typedef __bf16 bf16x8 __attribute__((ext_vector_type(8)));
typedef __bf16 bf16x2 __attribute__((ext_vector_type(2)));
typedef float  f32x4  __attribute__((ext_vector_type(4)));
typedef unsigned int u32x4 __attribute__((ext_vector_type(4)));

// ---------------- prep: VtS in STAGED order, UNSWIZZLED (B goes to registers now).
// VtS[((i*16+t32)*21+q)*512 + l*8 + e] = B value for row n=16q+(l>>2),
// kk = t32*32 + (l&3)*8 + e.  n<320 -> v[g,i*500+kk,k] (n=g*16+k);
// n==320 -> w[i*500+kk]; else 0. Zero-padded for kk>=500.
__global__ __launch_bounds__(256) void prep_vt(const float* __restrict__ v,
                                               const float* __restrict__ w,
                                               __bf16* __restrict__ VtS) {
  const int i = blockIdx.x / NFRG;
  const int q = blockIdx.x % NFRG;
  const int tdx = threadIdx.x;
  __shared__ float lv[FS * 17];
  if (q < NF) {  // panel for g=q: lv[s*17+k] = v[g, i*500+s, k]
    const int k = tdx & 15, sb = tdx >> 4;
    const float* vb = v + ((size_t)q * TFEAT + (size_t)i * FS) * KD;
    for (int it = 0; it < 32; ++it) {
      int s = it * 16 + sb;
      if (s < FS) lv[s * 17 + k] = vb[(size_t)s * KD + k];
    }
    __syncthreads();
  }
  const float* wf = w + (size_t)i * FS;
  __bf16* base = VtS + ((size_t)i * 16 * NFRG + q) * 512;
  for (int it = 0; it < 4; ++it) {
    int p = it * 256 + tdx;            // (t32,l) pair: 16*64 = 1024
    int t = p >> 6, l = p & 63;
    int r = l >> 2;                    // row within group (= k for q<20)
    int kk = t * 32 + (l & 3) * 8;
    bf16x8 h;
#pragma unroll
    for (int e = 0; e < 8; ++e) {
      int s = kk + e;
      float val = 0.f;
      if (s < FS) {
        if (q < NF) val = lv[s * 17 + r];
        else if (r == 0) val = wf[s];
      }
      h[e] = (__bf16)val;
    }
    *(bf16x8*)(base + (size_t)t * (NFRG * 512) + l * 8) = h;
  }
}

// ---------------- K1: per-field GEMM. BM=64, BN=336, BK=64, 8 K-steps.
// 512 threads = 8 waves; wave w owns frag-columns Fbase..Fbase+nfr-1
// (waves 0-4: 3 frags, waves 5-7: 2). acc[4][3] = 48 VGPR.
// B: per-wave global->VGPR dwordx4 loads from staged VtS (L2-resident), issued
//    a half-iter ahead, consumed via natural per-wave vmcnt deps. NO B LDS.
// A: LDS dbuf [2][64][72] reg-staged ping-pong distance-2 (HBM covered).
// ONE barrier per K-step, waiting ONLY lgkmcnt (ds ops) -- no global drain.
__global__ __launch_bounds__(512, 4) void k1_gemm(
    const float* __restrict__ x, const __bf16* __restrict__ VtS,
    __bf16* __restrict__ E2, int chunk_base, int tiles) {
  __shared__ __bf16 As[2][64][72];        // 18.4 KB (pad 64->72: no conflicts)

  int bid = blockIdx.x;
  const int nwg = gridDim.x;
  if ((nwg & 7) == 0) {                   // bijective XCD swizzle
    int cpx = nwg >> 3;
    bid = (bid & 7) * cpx + (bid >> 3);
  }
  const int i  = bid / tiles;
  const int tb = bid % tiles;
  const int tid = threadIdx.x;
  const int lane = tid & 63, wid = tid >> 6;
  const int b0 = chunk_base + tb * 64;

  // A stage (per thread): row = tid>>3 (0..63), 8 f32 cols at (tid&7)*8
  const int arow = tid >> 3;
  const int acol = (tid & 7) * 8;
  const float* xrow = x + (size_t)(b0 + arow) * TFEAT + i * FS;

  const int ar = lane & 15, akc = lane >> 4;
  const int Fbase = (wid < 5) ? 3 * wid : 15 + 2 * (wid - 5);
  const int nfr   = (wid < 5) ? 3 : 2;
  // per-lane fixed B offset: row ar, granule akc within a 1KB staged chunk
  const __bf16* vlane = VtS + (size_t)i * 16 * NFRG * 512
                      + (size_t)(ar * 4 + akc) * 8
                      + (size_t)Fbase * 512;

  f32x4 arA[2], arB[2];                   // ping-pong A prefetch (static names)
  auto aload = [&](int t, f32x4* r) {
    int c0 = t * 64 + acol;     if (c0 > 496) c0 = 496;  // junk pairs with 0-B
    int c1 = t * 64 + acol + 4; if (c1 > 496) c1 = 496;
    r[0] = *(const f32x4*)(xrow + c0);
    r[1] = *(const f32x4*)(xrow + c1);
  };
  auto astore = [&](int buf, const f32x4* r) {
    bf16x8 h;
#pragma unroll
    for (int e = 0; e < 4; ++e) {
      h[e] = (__bf16)r[0][e]; h[4 + e] = (__bf16)r[1][e];
    }
    *(bf16x8*)(&As[buf][arow][acol]) = h;
  };
  auto loadB = [&](int t32, bf16x8* bq) {
#pragma unroll
    for (int nf = 0; nf < 3; ++nf)
      if (nf < nfr)
        bq[nf] = *(const bf16x8*)(vlane + ((size_t)t32 * NFRG + nf) * 512);
  };

  f32x4 acc[4][3];
#pragma unroll
  for (int m = 0; m < 4; ++m)
#pragma unroll
    for (int nf = 0; nf < 3; ++nf) acc[m][nf] = (f32x4){0.f, 0.f, 0.f, 0.f};
  bf16x8 bqA[3], bqB[3];

  // prologue: tile0 staged from arA; tile1 -> arB (in flight); bqA(ks=0) issued
  aload(0, arA);
  astore(0, arA);                        // waits arA only (arB not yet issued)
  aload(1, arB);
  loadB(0, bqA);
  asm volatile("s_waitcnt lgkmcnt(0)" ::: "memory");
  __builtin_amdgcn_s_barrier();

  for (int t = 0; t < 8; ++t) {
    const int cur = t & 1;
    loadB(2 * t + 1, bqB);               // B ks=1, ages under astore+aload+ks0
    __builtin_amdgcn_sched_barrier(0);
    if (t < 7) {                         // store tile t+1 (regs 1 iter old: HBM ok)
      if (t & 1) astore(cur ^ 1, arA); else astore(cur ^ 1, arB);
    }
    if (t < 6) {                         // load tile t+2 into the other set
      if (t & 1) aload(t + 2, arB); else aload(t + 2, arA);
    }
    __builtin_amdgcn_sched_barrier(0);

    {                                    // ---- compute ks = 0 (uses bqA)
      bf16x8 af[4];
#pragma unroll
      for (int m = 0; m < 4; ++m)
        af[m] = *(const bf16x8*)(&As[cur][m * 16 + ar][akc * 8]);
#pragma unroll
      for (int nf = 0; nf < 3; ++nf)
        if (nf < nfr)
#pragma unroll
          for (int m = 0; m < 4; ++m)
            acc[m][nf] = __builtin_amdgcn_mfma_f32_16x16x32_bf16(af[m], bqA[nf],
                                                                 acc[m][nf], 0, 0, 0);
    }
    __builtin_amdgcn_sched_barrier(0);
    if (t < 7) loadB(2 * t + 2, bqA);    // B ks=0 of next tile, ages over ks1
    __builtin_amdgcn_sched_barrier(0);
    {                                    // ---- compute ks = 1 (uses bqB)
      bf16x8 af[4];
#pragma unroll
      for (int m = 0; m < 4; ++m)
        af[m] = *(const bf16x8*)(&As[cur][m * 16 + ar][32 + akc * 8]);
#pragma unroll
      for (int nf = 0; nf < 3; ++nf)
        if (nf < nfr)
#pragma unroll
          for (int m = 0; m < 4; ++m)
            acc[m][nf] = __builtin_amdgcn_mfma_f32_16x16x32_bf16(af[m], bqB[nf],
                                                                 acc[m][nf], 0, 0, 0);
    }
    if (t < 7) {
      asm volatile("s_waitcnt lgkmcnt(0)" ::: "memory");  // ds ops only!
      __builtin_amdgcn_s_barrier();      // single barrier, no vmcnt drain
    }
  }

  // epilogue: C/D layout col=lane&15, row=(lane>>4)*4+r
  const int lr4 = akc * 4, lcol = lane & 15;
#pragma unroll
  for (int m = 0; m < 4; ++m)
#pragma unroll
    for (int nf = 0; nf < 3; ++nf)
      if (nf < nfr) {
        int n = (Fbase + nf) * 16 + lcol;
#pragma unroll
        for (int r = 0; r < 4; ++r) {
          int bl = tb * 64 + m * 16 + lr4 + r;
          E2[(size_t)bl * ROWE + i * NCOL + n] = (__bf16)acc[m][nf][r];
        }
      }
}

// ---------------- K2: pair + linear reduction, 1 wave per batch row
__global__ __launch_bounds__(256) void k2_pair(
    const __bf16* __restrict__ E2, float* __restrict__ out, int chunk_base) {
  __shared__ __align__(16) unsigned shw[4][3360];  // 13440 B per wave
  const int tid = threadIdx.x, lane = tid & 63, wid = tid >> 6;
  const int bl = blockIdx.x * 4 + wid;
  const unsigned* src = (const unsigned*)(E2 + (size_t)bl * ROWE);
  for (int it = 0; it < 14; ++it) {
    int idx = it * 64 + lane;             // 16B units; 840 total
    if (idx < 840) {
      u32x4 val = *(const u32x4*)(src + (size_t)idx * 4);
      *(u32x4*)&shw[wid][idx * 4] = val;
    }
  }
  __syncthreads();
  const __bf16* sh = (const __bf16*)shw[wid];
  const int k = lane & 15, g = lane >> 4;
  float sum = 0.f;
  for (int i = g; i < NF; i += 4)
    for (int j = i + 1; j < NF; ++j)
      sum += (float)sh[i * NCOL + j * 16 + k] * (float)sh[j * NCOL + i * 16 + k];
  if (lane < NF) sum += (float)sh[lane * NCOL + 320];   // linear term
#pragma unroll
  for (int off = 32; off; off >>= 1) sum += __shfl_xor(sum, off);
  if (lane == 0) out[chunk_base + bl] = sum;
}

extern "C" void kernel_launch(void* const* d_in, const int* in_sizes, int n_in,
                              void* d_out, int out_size, void* d_ws, size_t ws_size,
                              hipStream_t stream) {
  const float* x = (const float*)d_in[0];
  const float* w = (const float*)d_in[1];
  const float* v = (const float*)d_in[2];
  float* out = (float*)d_out;
  char* ws = (char*)d_ws;

  const size_t vt_bytes = (size_t)NF * 16 * NFRG * 512 * 2;   // 6,881,280
  __bf16* VtS = (__bf16*)ws;
  __bf16* E2 = (__bf16*)(ws + vt_bytes);

  size_t eavail = (ws_size > vt_bytes) ? ws_size - vt_bytes : 0;
  int Bc = NB;
  while (Bc > 64 && (size_t)Bc * ROWE * 2 > eavail) Bc >>= 1;

  prep_vt<<<NF * NFRG, 256, 0, stream>>>(v, w, VtS);
  for (int cb = 0; cb < NB; cb += Bc) {
    int tiles = Bc / 64;
    k1_gemm<<<NF * tiles, 512, 0, stream>>>(x, VtS, E2, cb, tiles);
    k2_pair<<<Bc / 4, 256, 0, stream>>>(E2, out, cb);
  }
}